// Round 3
// baseline (206.788 us; speedup 1.0000x reference)
//
#include <hip/hip_runtime.h>
#include <stdint.h>

#define NS_ 4096
#define M_  8192
#define D_  256
#define TEMP 0.07f
#define EXP_SCALE 20.61707212818536f   // log2(e)/0.07 : exp(sim/T) = exp2(sim*EXP_SCALE)
#define LN2 0.6931471805599453f

typedef short bf16x8 __attribute__((ext_vector_type(8)));
typedef float f32x4  __attribute__((ext_vector_type(4)));
typedef unsigned short ushortx4 __attribute__((ext_vector_type(4)));

static __device__ inline unsigned short f2bf(float x) {
    unsigned u = __float_as_uint(x);
    u += 0x7fffu + ((u >> 16) & 1u);
    return (unsigned short)(u >> 16);
}

static __device__ inline float cleanf(float v) {
    return __builtin_isfinite(v) ? v : 0.0f;
}

// async 16B global -> LDS (lane-contiguous LDS destination required)
#define LDS_LOAD16(gp, lp) \
    __builtin_amdgcn_global_load_lds((const __attribute__((address_space(1))) uint32_t*)(gp), \
                                     (__attribute__((address_space(3))) uint32_t*)(lp), 16, 0, 0)

// ---------------- Kernel 1: clean + normalize -> bf16 F, fp32 pos[]; zero denom/cnt/out -
// grid = NS_/4, block = 256 (one wave per paired row; 4 row-pairs per block)
__global__ __launch_bounds__(256) void knorm(const float* __restrict__ z1,
                                             const float* __restrict__ z2,
                                             short* __restrict__ F,
                                             float* __restrict__ pos,
                                             float* __restrict__ denom,
                                             int* __restrict__ cnt,
                                             float* __restrict__ out) {
    const int wave = threadIdx.x >> 6;
    const int t    = threadIdx.x & 63;
    const int i    = blockIdx.x * 4 + wave;
    const float4* p1 = (const float4*)(z1 + (size_t)i * D_);
    const float4* p2 = (const float4*)(z2 + (size_t)i * D_);
    float4 a = p1[t], b = p2[t];
    a.x = cleanf(a.x); a.y = cleanf(a.y); a.z = cleanf(a.z); a.w = cleanf(a.w);
    b.x = cleanf(b.x); b.y = cleanf(b.y); b.z = cleanf(b.z); b.w = cleanf(b.w);

    float s1 = a.x*a.x + a.y*a.y + a.z*a.z + a.w*a.w;
    float s2 = b.x*b.x + b.y*b.y + b.z*b.z + b.w*b.w;
    float dp = a.x*b.x + a.y*b.y + a.z*b.z + a.w*b.w;
    #pragma unroll
    for (int m = 1; m < 64; m <<= 1) {
        s1 += __shfl_xor(s1, m);
        s2 += __shfl_xor(s2, m);
        dp += __shfl_xor(dp, m);
    }
    const float inv1 = 1.0f / fmaxf(sqrtf(s1), 1e-12f);
    const float inv2 = 1.0f / fmaxf(sqrtf(s2), 1e-12f);

    ushortx4 o1, o2;
    o1.x = f2bf(a.x * inv1); o1.y = f2bf(a.y * inv1); o1.z = f2bf(a.z * inv1); o1.w = f2bf(a.w * inv1);
    o2.x = f2bf(b.x * inv2); o2.y = f2bf(b.y * inv2); o2.z = f2bf(b.z * inv2); o2.w = f2bf(b.w * inv2);
    ((ushortx4*)(F + (size_t)i * D_))[t]          = o1;
    ((ushortx4*)(F + (size_t)(i + NS_) * D_))[t]  = o2;

    if (t == 0) pos[i] = dp * inv1 * inv2;       // exact fp32 positive sim
    if (t < 2)  denom[i * 2 + t] = 0.0f;         // zero denom (2 per row-pair x 4096)
    if (i == 0 && t < 32) cnt[t] = 0;            // zero rtile counters
    if (i == 0 && t == 0) out[0] = 0.0f;         // zero loss accumulator
}

// ---------------- Kernel 2: fused sim-GEMM + row exp-sums + finishers -------------------
// grid = 1024 = 32 rtiles (256 rows) x 32 col-blocks (256 cols). 256 thr / 4 waves.
// OCCUPANCY EXPERIMENT vs round 0: identical hot-loop structure (single 32KB buffer,
// 2-barrier staging rounds), but 256-col blocks -> 33 KB LDS x 4 blocks/CU = 133 KB,
// VGPR 128 -> 4 waves/SIMD: 16 waves/CU resident (was 8). Wave w owns 4 row-strips:
// rows R0 + ch*64 + w*16 (ch=0..3), A-frags K=256 resident (128 VGPR). B: 4 groups of
// 64 cols staged via global_load_lds, XOR-swizzled; each staged tile feeds 128 MFMAs/wave.
__global__ __launch_bounds__(256, 2) void kgemm(const short* __restrict__ F,
                                                float* __restrict__ denom,
                                                int* __restrict__ cnt,
                                                const float* __restrict__ pos,
                                                float* __restrict__ out) {
    __shared__ short Bl[64 * 256];   // 32 KB staging tile [row][k], 16B chunks swizzled
    __shared__ int lastflag;
    __shared__ float red[4];

    const int rtile = blockIdx.x >> 5;   // 32 rtiles
    const int cq    = blockIdx.x & 31;   // 32 col-blocks
    const int R0 = rtile * 256;
    const int C0 = cq * 256;

    const int tid  = threadIdx.x;
    const int lane = tid & 63;
    const int wave = tid >> 6;
    const int c16  = lane & 15;
    const int quad = lane >> 4;
    const int swz  = c16 & 7;

    // staging source offsets (shorts, relative to 64-row chunk base), XOR-swizzled
    int goff[8];
    #pragma unroll
    for (int r2 = 0; r2 < 8; ++r2) {
        int c    = tid + r2 * 256;
        int row  = c >> 5;
        int kg   = (c & 31) ^ (row & 7);
        goff[r2] = row * D_ + kg * 8;
    }

    // ---- A prologue: 4 chunks of 64 rows; wave w reads local rows w*16+c16 of each chunk
    bf16x8 afrag[4][8];
    const int arow_l = wave * 16 + c16;
    #pragma unroll
    for (int ch = 0; ch < 4; ++ch) {
        __syncthreads();
        const short* ga = F + (size_t)(R0 + ch * 64) * D_;
        #pragma unroll
        for (int r2 = 0; r2 < 8; ++r2)
            LDS_LOAD16(ga + goff[r2], Bl + (tid + r2 * 256) * 8);
        __syncthreads();
        #pragma unroll
        for (int ks = 0; ks < 8; ++ks)
            afrag[ch][ks] = *(const bf16x8*)(Bl + arow_l * 256 +
                                             (((ks * 4 + quad) ^ (arow_l & 7)) * 8));
    }

    float accexp[4][4];
    #pragma unroll
    for (int s = 0; s < 4; ++s)
        #pragma unroll
        for (int r = 0; r < 4; ++r) accexp[s][r] = 0.0f;

    // ---- main loop: 4 B-groups of 64 cols
    for (int it = 0; it < 4; ++it) {
        __syncthreads();                       // previous tile's reads done
        const short* gb = F + (size_t)(C0 + it * 64) * D_;
        #pragma unroll
        for (int r2 = 0; r2 < 8; ++r2)
            LDS_LOAD16(gb + goff[r2], Bl + (tid + r2 * 256) * 8);
        __syncthreads();                       // staging complete

        #pragma unroll
        for (int sub = 0; sub < 4; ++sub) {
            const int tc = sub * 16 + c16;     // tile col owned by this lane
            bf16x8 bfrag[8];
            #pragma unroll
            for (int ks = 0; ks < 8; ++ks)
                bfrag[ks] = *(const bf16x8*)(Bl + tc * 256 +
                                             (((ks * 4 + quad) ^ swz) * 8));
            f32x4 acc[4];
            #pragma unroll
            for (int s = 0; s < 4; ++s) acc[s] = (f32x4){0.f, 0.f, 0.f, 0.f};
            #pragma unroll
            for (int ks = 0; ks < 8; ++ks)
                #pragma unroll
                for (int s = 0; s < 4; ++s)
                    acc[s] = __builtin_amdgcn_mfma_f32_16x16x32_bf16(
                        afrag[s][ks], bfrag[ks], acc[s], 0, 0, 0);

            const int colbase = C0 + it * 64 + sub * 16;
            #pragma unroll
            for (int s = 0; s < 4; ++s) {
                const int rowbase = R0 + s * 64 + wave * 16;
                if (colbase != rowbase) {            // uniform fast path
                    #pragma unroll
                    for (int r = 0; r < 4; ++r)
                        accexp[s][r] += __builtin_amdgcn_exp2f(acc[s][r] * EXP_SCALE);
                } else {                             // diagonal 16x16 tile
                    #pragma unroll
                    for (int r = 0; r < 4; ++r) {
                        float e = __builtin_amdgcn_exp2f(acc[s][r] * EXP_SCALE);
                        if (c16 == quad * 4 + r) e = 0.0f;
                        accexp[s][r] += e;
                    }
                }
            }
        }
    }

    // row sums across the 16 lanes holding each row, one atomic per row
    #pragma unroll
    for (int s = 0; s < 4; ++s)
        #pragma unroll
        for (int r = 0; r < 4; ++r) {
            float v = accexp[s][r];
            v += __shfl_xor(v, 1);
            v += __shfl_xor(v, 2);
            v += __shfl_xor(v, 4);
            v += __shfl_xor(v, 8);
            if (c16 == 0)
                atomicAdd(&denom[R0 + s * 64 + wave * 16 + quad * 4 + r], v);
        }

    // last of 32 blocks per rtile: sum(log(denom[R0..R0+256))) / M -> out (+ pos term)
    __syncthreads();
    if (tid == 0) {
        __threadfence();                              // release our denom adds
        lastflag = (atomicAdd(&cnt[rtile], 1) == 31);
    }
    __syncthreads();
    if (lastflag) {
        __threadfence();                              // acquire others' denom adds
        float v = atomicAdd(&denom[R0 + tid], 0.0f);  // coherent read, 256 rows
        float p = __builtin_amdgcn_logf(v) * (LN2 / (float)M_);
        #pragma unroll
        for (int m = 1; m < 64; m <<= 1) p += __shfl_xor(p, m);
        if (lane == 0) red[wave] = p;
        __syncthreads();
        if (tid == 0) atomicAdd(out, red[0] + red[1] + red[2] + red[3]);
        if (rtile == 0) {                             // pos ready (knorm precedes)
            __syncthreads();                          // protect red reuse
            float sp = 0.0f;
            for (int i = tid; i < NS_; i += 256) sp += pos[i];
            #pragma unroll
            for (int m = 1; m < 64; m <<= 1) sp += __shfl_xor(sp, m);
            if (lane == 0) red[wave] = sp;
            __syncthreads();
            if (tid == 0)
                atomicAdd(out, (red[0] + red[1] + red[2] + red[3]) *
                               (-2.0f / (TEMP * (float)M_)));
        }
    }
}

extern "C" void kernel_launch(void* const* d_in, const int* in_sizes, int n_in,
                              void* d_out, int out_size, void* d_ws, size_t ws_size,
                              hipStream_t stream) {
    const float* z1 = (const float*)d_in[0];
    const float* z2 = (const float*)d_in[1];

    short* F     = (short*)d_ws;                                   // 4 MB
    float* denom = (float*)((char*)d_ws + (size_t)M_ * D_ * 2);    // 32 KB
    int*   cnt   = (int*)(denom + M_);                             // 128 B
    float* pos   = (float*)(cnt + 32);                             // 16 KB
    float* out   = (float*)d_out;

    knorm<<<NS_ / 4, 256, 0, stream>>>(z1, z2, F, pos, denom, cnt, out);
    kgemm<<<1024, 256, 0, stream>>>(F, denom, cnt, pos, out);
}

// Round 4
// 128.047 us; speedup vs baseline: 1.6149x; 1.6149x over previous
//
#include <hip/hip_runtime.h>
#include <stdint.h>

#define NS_ 4096
#define M_  8192
#define D_  256
#define TEMP 0.07f
#define EXP_SCALE 20.61707212818536f   // log2(e)/0.07 : exp(sim/T) = exp2(sim*EXP_SCALE)
#define LN2 0.6931471805599453f

typedef short bf16x8 __attribute__((ext_vector_type(8)));
typedef float f32x4  __attribute__((ext_vector_type(4)));
typedef unsigned short ushortx4 __attribute__((ext_vector_type(4)));

static __device__ inline unsigned short f2bf(float x) {
    unsigned u = __float_as_uint(x);
    u += 0x7fffu + ((u >> 16) & 1u);
    return (unsigned short)(u >> 16);
}

static __device__ inline float cleanf(float v) {
    return __builtin_isfinite(v) ? v : 0.0f;
}

// async 16B global -> LDS (lane-contiguous LDS destination required)
#define LDS_LOAD16(gp, lp) \
    __builtin_amdgcn_global_load_lds((const __attribute__((address_space(1))) uint32_t*)(gp), \
                                     (__attribute__((address_space(3))) uint32_t*)(lp), 16, 0, 0)

// ---------------- Kernel 1: clean + normalize -> bf16 F, fp32 pos[]; zero denom/cnt/out -
// grid = NS_/4, block = 256 (one wave per paired row; 4 row-pairs per block)
__global__ __launch_bounds__(256) void knorm(const float* __restrict__ z1,
                                             const float* __restrict__ z2,
                                             short* __restrict__ F,
                                             float* __restrict__ pos,
                                             float* __restrict__ denom,
                                             int* __restrict__ cnt,
                                             float* __restrict__ out) {
    const int wave = threadIdx.x >> 6;
    const int t    = threadIdx.x & 63;
    const int i    = blockIdx.x * 4 + wave;
    const float4* p1 = (const float4*)(z1 + (size_t)i * D_);
    const float4* p2 = (const float4*)(z2 + (size_t)i * D_);
    float4 a = p1[t], b = p2[t];
    a.x = cleanf(a.x); a.y = cleanf(a.y); a.z = cleanf(a.z); a.w = cleanf(a.w);
    b.x = cleanf(b.x); b.y = cleanf(b.y); b.z = cleanf(b.z); b.w = cleanf(b.w);

    float s1 = a.x*a.x + a.y*a.y + a.z*a.z + a.w*a.w;
    float s2 = b.x*b.x + b.y*b.y + b.z*b.z + b.w*b.w;
    float dp = a.x*b.x + a.y*b.y + a.z*b.z + a.w*b.w;
    #pragma unroll
    for (int m = 1; m < 64; m <<= 1) {
        s1 += __shfl_xor(s1, m);
        s2 += __shfl_xor(s2, m);
        dp += __shfl_xor(dp, m);
    }
    const float inv1 = 1.0f / fmaxf(sqrtf(s1), 1e-12f);
    const float inv2 = 1.0f / fmaxf(sqrtf(s2), 1e-12f);

    ushortx4 o1, o2;
    o1.x = f2bf(a.x * inv1); o1.y = f2bf(a.y * inv1); o1.z = f2bf(a.z * inv1); o1.w = f2bf(a.w * inv1);
    o2.x = f2bf(b.x * inv2); o2.y = f2bf(b.y * inv2); o2.z = f2bf(b.z * inv2); o2.w = f2bf(b.w * inv2);
    ((ushortx4*)(F + (size_t)i * D_))[t]          = o1;
    ((ushortx4*)(F + (size_t)(i + NS_) * D_))[t]  = o2;

    if (t == 0) pos[i] = dp * inv1 * inv2;       // exact fp32 positive sim
    if (t < 2)  denom[i * 2 + t] = 0.0f;         // zero denom (2 per row-pair x 4096)
    if (i == 0 && t < 32) cnt[t] = 0;            // zero rtile counters
    if (i == 0 && t == 0) out[0] = 0.0f;         // zero loss accumulator
}

// ---------------- Kernel 2: TRIANGULAR fused sim-GEMM + row/col exp-sums + finishers ----
// sim = F F^T is symmetric: only tile-pairs (ri <= rj) at 256x256 granularity computed.
// grid = 32x32 = 1024 blocks, (bid>>5, bid&31) = (ri, rj); blocks with rj < ri return
// (528 live blocks ~= 2/CU, preserving round-0's healthy L2 regime). 256 thr / 4 waves.
// For ri < rj each exp value feeds BOTH row-sums (rows of ri, shfl over c16) and
// col-sums (rows of rj: quad-reduce in fragment -> per-wave LDS column accumulators).
// Diagonal blocks: masked row-sums only (covers both orientations already).
// A-frags are loaded DIRECTLY from global (lane c16 = row, quad = k-chunk: 64B
// contiguous per 4 lanes) — no A prologue staging/barriers. B staged via
// global_load_lds, XOR-swizzled, single 32KB buffer (round-0 proven path).
// cnt fan-in per rtile r = 1 diag + (31-r) row-blocks + r col-blocks = 32 exactly.
__global__ __launch_bounds__(256, 2) void kgemm(const short* __restrict__ F,
                                                float* __restrict__ denom,
                                                int* __restrict__ cnt,
                                                const float* __restrict__ pos,
                                                float* __restrict__ out) {
    __shared__ short Bl[64 * 256];      // 32 KB B staging tile [col][k], 16B chunks swizzled
    __shared__ float colacc[4][256];    // 4 KB per-wave column-sum accumulators
    __shared__ int finmask;
    __shared__ float red[4];

    const int ri = blockIdx.x >> 5;      // 32 rtile rows
    const int rj = blockIdx.x & 31;      // 32 rtile cols
    if (rj < ri) return;                 // below diagonal: symmetric partner covers it
    const bool isdiag = (ri == rj);
    const int R0 = ri * 256;
    const int C0 = rj * 256;

    const int tid  = threadIdx.x;
    const int lane = tid & 63;
    const int wave = tid >> 6;
    const int c16  = lane & 15;
    const int quad = lane >> 4;
    const int swz  = c16 & 7;

    // staging source offsets (shorts, relative to 64-col tile base), XOR-swizzled
    int goff[8];
    #pragma unroll
    for (int r2 = 0; r2 < 8; ++r2) {
        int c    = tid + r2 * 256;
        int row  = c >> 5;
        int kg   = (c & 31) ^ (row & 7);
        goff[r2] = row * D_ + kg * 8;
    }

    // ---- A: direct global loads, no LDS bounce. Lane (c16,quad): row R0+ch*64+wave*16+c16,
    // k-chunk (ks*4+quad)*8 — 4 quad-lanes form 64B contiguous per (row,ks).
    bf16x8 afrag[4][8];
    #pragma unroll
    for (int ch = 0; ch < 4; ++ch) {
        const short* ga = F + (size_t)(R0 + ch * 64 + wave * 16 + c16) * D_;
        #pragma unroll
        for (int ks = 0; ks < 8; ++ks)
            afrag[ch][ks] = *(const bf16x8*)(ga + (ks * 4 + quad) * 8);
    }

    // init per-wave column accumulators (barrier before first use is in the main loop)
    #pragma unroll
    for (int q = 0; q < 4; ++q) colacc[q][tid & 255] = (tid < 256) ? 0.0f : 0.0f;
    #pragma unroll
    for (int q = 0; q < 4; ++q) colacc[q][tid] = 0.0f;

    float accexp[4][4];
    #pragma unroll
    for (int s = 0; s < 4; ++s)
        #pragma unroll
        for (int r = 0; r < 4; ++r) accexp[s][r] = 0.0f;

    // ---- main loop: 4 B-groups of 64 cols from rtile rj
    for (int it = 0; it < 4; ++it) {
        __syncthreads();                       // previous tile's reads done / colacc init done
        const short* gb = F + (size_t)(C0 + it * 64) * D_;
        #pragma unroll
        for (int r2 = 0; r2 < 8; ++r2)
            LDS_LOAD16(gb + goff[r2], Bl + (tid + r2 * 256) * 8);
        __syncthreads();                       // staging complete

        #pragma unroll
        for (int sub = 0; sub < 4; ++sub) {
            const int tc = sub * 16 + c16;     // tile col owned by this lane
            bf16x8 bfrag[8];
            #pragma unroll
            for (int ks = 0; ks < 8; ++ks)
                bfrag[ks] = *(const bf16x8*)(Bl + tc * 256 +
                                             (((ks * 4 + quad) ^ swz) * 8));
            f32x4 acc[4];
            #pragma unroll
            for (int s = 0; s < 4; ++s) acc[s] = (f32x4){0.f, 0.f, 0.f, 0.f};
            #pragma unroll
            for (int ks = 0; ks < 8; ++ks)
                #pragma unroll
                for (int s = 0; s < 4; ++s)
                    acc[s] = __builtin_amdgcn_mfma_f32_16x16x32_bf16(
                        afrag[s][ks], bfrag[ks], acc[s], 0, 0, 0);

            if (!isdiag) {
                // off-diagonal: every exp feeds row-sum (rows of ri) AND col-sum (rows of rj)
                float colpart = 0.0f;
                #pragma unroll
                for (int s = 0; s < 4; ++s)
                    #pragma unroll
                    for (int r = 0; r < 4; ++r) {
                        float e = __builtin_amdgcn_exp2f(acc[s][r] * EXP_SCALE);
                        accexp[s][r] += e;
                        colpart += e;
                    }
                // reduce over the 4 quads holding this column (lanes c16, c16+16, +32, +48)
                colpart += __shfl_xor(colpart, 16);
                colpart += __shfl_xor(colpart, 32);
                if (quad == 0)
                    colacc[wave][it * 64 + sub * 16 + c16] += colpart;  // wave-private row
            } else {
                const int colbase = C0 + it * 64 + sub * 16;
                #pragma unroll
                for (int s = 0; s < 4; ++s) {
                    const int rowbase = R0 + s * 64 + wave * 16;
                    if (colbase != rowbase) {
                        #pragma unroll
                        for (int r = 0; r < 4; ++r)
                            accexp[s][r] += __builtin_amdgcn_exp2f(acc[s][r] * EXP_SCALE);
                    } else {                     // diagonal 16x16 tile: zero self-pairs
                        #pragma unroll
                        for (int r = 0; r < 4; ++r) {
                            float e = __builtin_amdgcn_exp2f(acc[s][r] * EXP_SCALE);
                            if (c16 == quad * 4 + r) e = 0.0f;
                            accexp[s][r] += e;
                        }
                    }
                }
            }
        }
    }

    // row sums across the 16 lanes holding each row, one atomic per row (rows of ri)
    #pragma unroll
    for (int s = 0; s < 4; ++s)
        #pragma unroll
        for (int r = 0; r < 4; ++r) {
            float v = accexp[s][r];
            v += __shfl_xor(v, 1);
            v += __shfl_xor(v, 2);
            v += __shfl_xor(v, 4);
            v += __shfl_xor(v, 8);
            if (c16 == 0)
                atomicAdd(&denom[R0 + s * 64 + wave * 16 + quad * 4 + r], v);
        }

    // column sums -> rows of rj (transpose contribution), one atomic per col
    if (!isdiag) {
        __syncthreads();                       // all waves' colacc RMWs visible
        float cs = colacc[0][tid] + colacc[1][tid] + colacc[2][tid] + colacc[3][tid];
        atomicAdd(&denom[C0 + tid], cs);
    }

    // ---- finishers: each rtile completes after its 32 contributors arrive
    __syncthreads();
    if (tid == 0) {
        __threadfence();                              // release our denom adds
        int m = 0;
        if (atomicAdd(&cnt[ri], 1) == 31) m |= 1;
        if (!isdiag && atomicAdd(&cnt[rj], 1) == 31) m |= 2;
        finmask = m;
    }
    __syncthreads();
    #pragma unroll
    for (int f = 0; f < 2; ++f) {
        if (finmask & (1 << f)) {                     // uniform branch
            const int rt = f ? rj : ri;
            __threadfence();                          // acquire others' denom adds
            float v = atomicAdd(&denom[rt * 256 + tid], 0.0f);  // coherent read
            float p = __builtin_amdgcn_logf(v) * (LN2 / (float)M_);
            #pragma unroll
            for (int m = 1; m < 64; m <<= 1) p += __shfl_xor(p, m);
            if (lane == 0) red[wave] = p;
            __syncthreads();
            if (tid == 0) atomicAdd(out, red[0] + red[1] + red[2] + red[3]);
            if (rt == 0) {                            // pos ready (knorm precedes)
                __syncthreads();                      // protect red reuse
                float sp = 0.0f;
                for (int ii = tid; ii < NS_; ii += 256) sp += pos[ii];
                #pragma unroll
                for (int m = 1; m < 64; m <<= 1) sp += __shfl_xor(sp, m);
                if (lane == 0) red[wave] = sp;
                __syncthreads();
                if (tid == 0)
                    atomicAdd(out, (red[0] + red[1] + red[2] + red[3]) *
                                   (-2.0f / (TEMP * (float)M_)));
            }
            __syncthreads();                          // protect red before 2nd finisher
        }
    }
}

extern "C" void kernel_launch(void* const* d_in, const int* in_sizes, int n_in,
                              void* d_out, int out_size, void* d_ws, size_t ws_size,
                              hipStream_t stream) {
    const float* z1 = (const float*)d_in[0];
    const float* z2 = (const float*)d_in[1];

    short* F     = (short*)d_ws;                                   // 4 MB
    float* denom = (float*)((char*)d_ws + (size_t)M_ * D_ * 2);    // 32 KB
    int*   cnt   = (int*)(denom + M_);                             // 128 B
    float* pos   = (float*)(cnt + 32);                             // 16 KB
    float* out   = (float*)d_out;

    knorm<<<NS_ / 4, 256, 0, stream>>>(z1, z2, F, pos, denom, cnt, out);
    kgemm<<<1024, 256, 0, stream>>>(F, denom, cnt, pos, out);
}